// Round 1
// baseline (328.477 us; speedup 1.0000x reference)
//
#include <hip/hip_runtime.h>

#define LSEQ 2048
#define DM   1024
#define NH   16

typedef __attribute__((ext_vector_type(8))) short bf16x8;
typedef __attribute__((ext_vector_type(4))) float f32x4;

static __device__ __forceinline__ unsigned short f2bf(float f) {
  unsigned int u = __float_as_uint(f);
  u += 0x7FFFu + ((u >> 16) & 1u);
  return (unsigned short)(u >> 16);
}

static __device__ __forceinline__ void gld_lds16(const unsigned short* g, unsigned short* l) {
  __builtin_amdgcn_global_load_lds(
      (const __attribute__((address_space(1))) unsigned int*)g,
      (__attribute__((address_space(3))) unsigned int*)l, 16, 0, 0);
}

// ---------------- data fp32 -> bf16 ----------------
__global__ void k_convert_data(const float* __restrict__ src,
                               unsigned short* __restrict__ dst, int n4) {
  int i = blockIdx.x * 256 + threadIdx.x;
  if (i >= n4) return;
  float4 v = reinterpret_cast<const float4*>(src)[i];
  ushort4 o;
  o.x = f2bf(v.x); o.y = f2bf(v.y); o.z = f2bf(v.z); o.w = f2bf(v.w);
  reinterpret_cast<ushort4*>(dst)[i] = o;
}

// ---------------- W -> Wt bf16 (transpose to [n][k]) ----------------
__global__ void k_transpose_w(const float* __restrict__ Wq,
                              const float* __restrict__ Wk,
                              const float* __restrict__ Wv,
                              unsigned short* __restrict__ Wt) {
  __shared__ unsigned short tile[64][65];
  const float* W = (blockIdx.z == 0) ? Wq : (blockIdx.z == 1) ? Wk : Wv;
  int n0 = blockIdx.x * 64, k0 = blockIdx.y * 64;
  int t = threadIdx.x;
  int c = t & 63, r0 = t >> 6;
  for (int i = 0; i < 16; ++i) {
    int r = r0 + i * 4;
    tile[r][c] = f2bf(W[(size_t)(k0 + r) * DM + n0 + c]);
  }
  __syncthreads();
  size_t nbase = (size_t)blockIdx.z * DM + n0;
  for (int i = 0; i < 16; ++i) {
    int n = r0 + i * 4;
    Wt[(nbase + n) * DM + k0 + c] = tile[c][n];
  }
}

// ---------------- fused QKV GEMM + bias + rotary + layout ----------------
// A: data bf16 [4096][1024]; Bt: Wt bf16 [3072][1024] (q|k|v, n-major)
// qbuf/kbuf: [32 bh][2048][64] bf16 ; vtbuf: [32 bh][64][2048] bf16
__global__ __launch_bounds__(256) void k_qkv_gemm(
    const unsigned short* __restrict__ A, const unsigned short* __restrict__ Bt,
    const float* __restrict__ bq, const float* __restrict__ bk,
    const float* __restrict__ bv, const float* __restrict__ temporal,
    unsigned short* __restrict__ qbuf, unsigned short* __restrict__ kbuf,
    unsigned short* __restrict__ vtbuf) {
  __shared__ unsigned short As[128 * 32];
  __shared__ unsigned short Bs[128 * 32];
  const int tid = threadIdx.x;
  const int lane = tid & 63, wid = tid >> 6;
  const int wm = wid >> 1, wn = wid & 1;
  const int lr = lane & 15, lg = lane >> 4;
  const int m0 = blockIdx.x * 128;
  const int n0 = blockIdx.y * 128;

  f32x4 acc[4][4] = {};

  const int e0 = tid * 8;
  const int e1 = (256 + tid) * 8;
  const int ra0 = e0 >> 5, ca0 = e0 & 31;
  const int ra1 = e1 >> 5, ca1 = e1 & 31;
  unsigned short* lA0 = As + wid * 512;
  unsigned short* lA1 = As + 2048 + wid * 512;
  unsigned short* lB0 = Bs + wid * 512;
  unsigned short* lB1 = Bs + 2048 + wid * 512;

  for (int k0 = 0; k0 < DM; k0 += 32) {
    __syncthreads();
    gld_lds16(A + (size_t)(m0 + ra0) * DM + k0 + ca0, lA0);
    gld_lds16(A + (size_t)(m0 + ra1) * DM + k0 + ca1, lA1);
    gld_lds16(Bt + (size_t)(n0 + ra0) * DM + k0 + ca0, lB0);
    gld_lds16(Bt + (size_t)(n0 + ra1) * DM + k0 + ca1, lB1);
    __syncthreads();
    bf16x8 af[4], bfv[4];
    for (int mi = 0; mi < 4; ++mi)
      af[mi] = *reinterpret_cast<const bf16x8*>(As + (wm * 64 + mi * 16 + lr) * 32 + lg * 8);
    for (int ni = 0; ni < 4; ++ni)
      bfv[ni] = *reinterpret_cast<const bf16x8*>(Bs + (wn * 64 + ni * 16 + lr) * 32 + lg * 8);
    for (int mi = 0; mi < 4; ++mi)
      for (int ni = 0; ni < 4; ++ni)
        acc[mi][ni] = __builtin_amdgcn_mfma_f32_16x16x32_bf16(af[mi], bfv[ni], acc[mi][ni], 0, 0, 0);
  }

  // epilogue: bias (+rotary for q,k) and scatter
  for (int mi = 0; mi < 4; ++mi) {
    const int mrow_base = m0 + wm * 64 + mi * 16 + lg * 4;
    for (int ni = 0; ni < 4; ++ni) {
      const int ng = n0 + wn * 64 + ni * 16 + lr;   // 0..3071
      const int mat = ng >> 10;                     // 0=q 1=k 2=v (wave-uniform)
      const int c = ng & 1023;
      const int h = c >> 6, d = c & 63;
      const float bias = (mat == 0 ? bq : mat == 1 ? bk : bv)[c];
      f32x4 v = acc[mi][ni];
      if (mat < 2) {
        unsigned short* obuf = (mat == 0) ? qbuf : kbuf;
        const int jj = d & 15, tt = d >> 4;
        // f = 10000^(-(jj&~1)/16) = exp(-(jj&14)*ln(1e4)/16)
        const float fr = __expf(-(float)(jj & 14) * 0.5756462732485115f);
        const float sign = (d & 1) ? 1.f : -1.f;
        for (int j = 0; j < 4; ++j) {
          const int mrow = mrow_base + j;
          const float x = v[j] + bias;
          const float part = __shfl_xor(x, 1, 64);   // partner col d^1 (its own bias added)
          const int bb = mrow >> 11, lq = mrow & 2047;
          const float fq = temporal[((size_t)bb * LSEQ + lq) * 4 + tt] * fr;
          float sn, cs;
          __sincosf(fq, &sn, &cs);
          const float outv = x * cs + sign * part * sn;
          obuf[(((size_t)(bb * NH + h)) * LSEQ + lq) * 64 + d] = f2bf(outv);
        }
      } else {
        for (int j = 0; j < 4; ++j) {
          const int mrow = mrow_base + j;
          const int bb = mrow >> 11, lq = mrow & 2047;
          vtbuf[(((size_t)(bb * NH + h)) * 64 + d) * LSEQ + lq] = f2bf(v[j] + bias);
        }
      }
    }
  }
}

// ---------------- flash attention ----------------
// grid: (32 q-tiles, 32 bh); block 256 = 4 waves x 16 q-rows
__global__ __launch_bounds__(256) void k_attn(
    const unsigned short* __restrict__ qbuf, const unsigned short* __restrict__ kbuf,
    const unsigned short* __restrict__ vtbuf, const float* __restrict__ mask,
    float* __restrict__ out) {
  __shared__ unsigned short Ps[4][16 * 72];   // per-wave P tile, padded rows (144B)
  const int tid = threadIdx.x, lane = tid & 63, wid = tid >> 6;
  const int lr = lane & 15, lg = lane >> 4;
  const int bh = blockIdx.y;
  const int q0 = blockIdx.x * 64 + wid * 16;
  const size_t bhL = (size_t)bh * LSEQ;

  bf16x8 qf[2];
  for (int kk = 0; kk < 2; ++kk)
    qf[kk] = *reinterpret_cast<const bf16x8*>(qbuf + (bhL + q0 + lr) * 64 + kk * 32 + lg * 8);

  float m_run[4], l_run[4];
  f32x4 o[4] = {};
  for (int j = 0; j < 4; ++j) { m_run[j] = -1e30f; l_run[j] = 0.f; }

  for (int kv0 = 0; kv0 < LSEQ; kv0 += 64) {
    // S = Q K^T for 16x64
    f32x4 s[4] = {};
    for (int ni = 0; ni < 4; ++ni)
      for (int kk = 0; kk < 2; ++kk) {
        bf16x8 kf = *reinterpret_cast<const bf16x8*>(
            kbuf + (bhL + kv0 + ni * 16 + lr) * 64 + kk * 32 + lg * 8);
        s[ni] = __builtin_amdgcn_mfma_f32_16x16x32_bf16(qf[kk], kf, s[ni], 0, 0, 0);
      }
    // scale + mask
    float sv[4][4];
    for (int ni = 0; ni < 4; ++ni)
      for (int j = 0; j < 4; ++j) {
        const int qg = q0 + lg * 4 + j;
        const int kg = kv0 + ni * 16 + lr;
        sv[ni][j] = s[ni][j] * 0.125f + mask[(size_t)qg * LSEQ + kg];
      }
    // online softmax (rows split 4 per lane-group; reduce across 16 lanes)
    for (int j = 0; j < 4; ++j) {
      float mt = fmaxf(fmaxf(sv[0][j], sv[1][j]), fmaxf(sv[2][j], sv[3][j]));
      mt = fmaxf(mt, __shfl_xor(mt, 1, 64));
      mt = fmaxf(mt, __shfl_xor(mt, 2, 64));
      mt = fmaxf(mt, __shfl_xor(mt, 4, 64));
      mt = fmaxf(mt, __shfl_xor(mt, 8, 64));
      const float mn = fmaxf(m_run[j], mt);
      const float alpha = __expf(m_run[j] - mn);
      m_run[j] = mn;
      float rs = 0.f;
      for (int ni = 0; ni < 4; ++ni) {
        const float p = __expf(sv[ni][j] - mn);
        sv[ni][j] = p;
        rs += p;
      }
      rs += __shfl_xor(rs, 1, 64);
      rs += __shfl_xor(rs, 2, 64);
      rs += __shfl_xor(rs, 4, 64);
      rs += __shfl_xor(rs, 8, 64);
      l_run[j] = l_run[j] * alpha + rs;
      for (int di = 0; di < 4; ++di) o[di][j] *= alpha;
    }
    // P (C-layout) -> LDS -> A-layout fragments
    unsigned short* ps = &Ps[wid][0];
    for (int ni = 0; ni < 4; ++ni)
      for (int j = 0; j < 4; ++j)
        ps[(lg * 4 + j) * 72 + ni * 16 + lr] = f2bf(sv[ni][j]);
    __syncthreads();
    bf16x8 pf[2];
    for (int kk = 0; kk < 2; ++kk)
      pf[kk] = *reinterpret_cast<const bf16x8*>(ps + lr * 72 + kk * 32 + lg * 8);
    // O += P V  (V^T layout: 8 contiguous kv per lane)
    for (int di = 0; di < 4; ++di)
      for (int kk = 0; kk < 2; ++kk) {
        bf16x8 vf = *reinterpret_cast<const bf16x8*>(
            vtbuf + ((size_t)bh * 64 + di * 16 + lr) * LSEQ + kv0 + kk * 32 + lg * 8);
        o[di] = __builtin_amdgcn_mfma_f32_16x16x32_bf16(pf[kk], vf, o[di], 0, 0, 0);
      }
  }
  // normalize + write fp32 out[b][l][h*64+d]
  const int b = bh >> 4, h = bh & 15;
  for (int di = 0; di < 4; ++di)
    for (int j = 0; j < 4; ++j) {
      const int qg = q0 + lg * 4 + j;
      out[((size_t)(b * LSEQ) + qg) * DM + h * 64 + di * 16 + lr] = o[di][j] / l_run[j];
    }
}

extern "C" void kernel_launch(void* const* d_in, const int* in_sizes, int n_in,
                              void* d_out, int out_size, void* d_ws, size_t ws_size,
                              hipStream_t stream) {
  const float* data     = (const float*)d_in[0];
  const float* temporal = (const float*)d_in[1];
  const float* mask     = (const float*)d_in[2];
  const float* Wq       = (const float*)d_in[3];
  const float* bq       = (const float*)d_in[4];
  const float* Wk       = (const float*)d_in[5];
  const float* bk       = (const float*)d_in[6];
  const float* Wv       = (const float*)d_in[7];
  const float* bv       = (const float*)d_in[8];
  float* out = (float*)d_out;

  char* ws = (char*)d_ws;
  unsigned short* data_bf = (unsigned short*)(ws);                        // 8 MB
  unsigned short* wt      = (unsigned short*)(ws + (size_t)8  * 1048576); // 6 MB
  unsigned short* qbuf    = (unsigned short*)(ws + (size_t)14 * 1048576); // 8 MB
  unsigned short* kbuf    = (unsigned short*)(ws + (size_t)22 * 1048576); // 8 MB
  unsigned short* vtbuf   = (unsigned short*)(ws + (size_t)30 * 1048576); // 8 MB

  hipLaunchKernelGGL(k_convert_data, dim3(4096), dim3(256), 0, stream,
                     data, data_bf, (2 * LSEQ * DM) / 4);
  hipLaunchKernelGGL(k_transpose_w, dim3(16, 16, 3), dim3(256), 0, stream,
                     Wq, Wk, Wv, wt);
  hipLaunchKernelGGL(k_qkv_gemm, dim3(32, 24), dim3(256), 0, stream,
                     data_bf, wt, bq, bk, bv, temporal, qbuf, kbuf, vtbuf);
  hipLaunchKernelGGL(k_attn, dim3(32, 32), dim3(256), 0, stream,
                     qbuf, kbuf, vtbuf, mask, out);
}